// Round 23
// baseline (963.922 us; speedup 1.0000x reference)
//
#include <hip/hip_runtime.h>
#include <math.h>

#define N_NODES 100000
#define NPG     12500
#define EPG     200000
#define EPG_TOT 212500   // per-graph edges incl self-loops
#define E_TOT   1700000
#define C1      512
#define NB_SCAN 98   // ceil(100000/1024)
#define NSTRIPE 64   // stats striping
#define NCHUNK  8    // count_deg chunks per graph
#define CHUNK   26563  // ceil(EPG_TOT / NCHUNK)

static inline int cdiv(int a, int b){ return (a + b - 1) / b; }

// ---------- ordered-float encoding for atomic max (pool7 only) ----------
__device__ __forceinline__ unsigned fenc(float f){
  unsigned u = __float_as_uint(f);
  return (u >> 31) ? ~u : (u | 0x80000000u);
}
__device__ __forceinline__ float fdec(unsigned e){
  return (e & 0x80000000u) ? __uint_as_float(e ^ 0x80000000u) : __uint_as_float(~e);
}

__device__ __forceinline__ float elu1(float v){ return v > 0.f ? v : expm1f(v); }

// ---------- utility ----------
__global__ void zero_kernel(int* __restrict__ p, int n){
  int i = blockIdx.x * 256 + threadIdx.x;
  if (i < n) p[i] = 0;
}

// ---------- degree count + edge ranks: LDS counting, 8 chunks/graph ----------
__global__ __launch_bounds__(1024) void count_deg(
    const int* __restrict__ dst, int* __restrict__ deg,
    unsigned short* __restrict__ ernk){
  __shared__ int ldeg[NPG];
  __shared__ int lbase[NPG];
  int g = blockIdx.x & 7;
  int chunk = blockIdx.x >> 3;
  int t = threadIdx.x;
  for (int j = t; j < NPG; j += 1024) ldeg[j] = 0;
  __syncthreads();
  int i0 = chunk * CHUNK;
  int i1 = min(i0 + CHUNK, EPG_TOT);
  for (int idx = i0 + t; idx < i1; idx += 1024){
    int dl = (idx < EPG) ? (dst[g * EPG + idx] - g * NPG) : (idx - EPG);
    int p = atomicAdd(&ldeg[dl], 1);
    ernk[(size_t)g * EPG_TOT + idx] = (unsigned short)p;   // local rank
  }
  __syncthreads();
  for (int j = t; j < NPG; j += 1024){
    int cnt = ldeg[j];
    lbase[j] = cnt ? atomicAdd(&deg[g * NPG + j], cnt) : 0;  // contiguous atomics
  }
  __syncthreads();
  for (int idx = i0 + t; idx < i1; idx += 1024){
    int dl = (idx < EPG) ? (dst[g * EPG + idx] - g * NPG) : (idx - EPG);
    ernk[(size_t)g * EPG_TOT + idx] += (unsigned short)lbase[dl];
  }
}

__global__ void scan1(const int* __restrict__ deg, int* __restrict__ row_start,
                      int* __restrict__ partials){
  __shared__ int sm[256];
  int t = threadIdx.x, b = blockIdx.x;
  int base = b * 1024 + t * 4;
  int d0 = (base + 0 < N_NODES) ? deg[base + 0] : 0;
  int d1 = (base + 1 < N_NODES) ? deg[base + 1] : 0;
  int d2 = (base + 2 < N_NODES) ? deg[base + 2] : 0;
  int d3 = (base + 3 < N_NODES) ? deg[base + 3] : 0;
  int s = d0 + d1 + d2 + d3;
  sm[t] = s; __syncthreads();
  for (int off = 1; off < 256; off <<= 1){
    int v = (t >= off) ? sm[t - off] : 0;
    __syncthreads();
    sm[t] += v;
    __syncthreads();
  }
  int excl = sm[t] - s;
  if (base + 0 < N_NODES) row_start[base + 0] = excl;
  if (base + 1 < N_NODES) row_start[base + 1] = excl + d0;
  if (base + 2 < N_NODES) row_start[base + 2] = excl + d0 + d1;
  if (base + 3 < N_NODES) row_start[base + 3] = excl + d0 + d1 + d2;
  if (t == 255) partials[b] = sm[255];
}

__global__ void scan2(int* __restrict__ partials){
  if (threadIdx.x == 0 && blockIdx.x == 0){
    int acc = 0;
    for (int i = 0; i < NB_SCAN; i++){ int v = partials[i]; partials[i] = acc; acc += v; }
  }
}

__global__ void scan3(int* __restrict__ row_start, const int* __restrict__ partials){
  int i = blockIdx.x * 256 + threadIdx.x;
  if (i < N_NODES) row_start[i] += partials[i >> 10];
  if (i == 0) row_start[N_NODES] = E_TOT;
}

// fill CSR: atomic-free (rank precomputed in count_deg); u16 graph-local src.
__global__ void fill_csr(const int* __restrict__ src, const int* __restrict__ dst,
                         const int* __restrict__ clus, const unsigned short* __restrict__ ernk,
                         const int* __restrict__ row_start,
                         unsigned short* __restrict__ col, int* __restrict__ pf){
  int g = blockIdx.x & 7;
  int idx = (blockIdx.x >> 3) * 256 + threadIdx.x;
  if (idx >= EPG_TOT) return;
  int s, d;
  if (idx < EPG){ int e = g * EPG + idx; s = src[e]; d = dst[e]; }
  else { s = d = g * NPG + idx - EPG; }    // self-loop segment
  int p = ernk[(size_t)g * EPG_TOT + idx];
  col[row_start[d] + p] = (unsigned short)(s - g * NPG);
  pf[clus[d] * 64 + (clus[s] & 63)] = 1;   // fused coarse pair-dedup
}

// ---------- tiled GEMM: out[n,COUT] = stage(in[n,CIN]) @ w (+ pos @ w3) -----
// Weight access w[(k+i)*COUT + c] is lane-coalesced and optimal (R17 transposed
// layout was 2x slower). R=8: 20KB LDS keeps occupancy (R=16 measured worse).
template<int R, int CIN, int COUT, bool FIX, bool STATS, bool BNIN, bool POSW, bool GSWZ>
__global__ __launch_bounds__(256) void gemm_tile(
    const float* __restrict__ in, const float* __restrict__ w,
    const float* __restrict__ ss, const float* __restrict__ resid,
    float* __restrict__ side, const float* __restrict__ posn,
    const float* __restrict__ w3p, float* __restrict__ out,
    float* __restrict__ stat, int n){
  constexpr int CPL = (COUT + 63) / 64;
  __shared__ float lds[4][R * CIN];
  __shared__ float sred[STATS ? 8 * COUT : 1];
  int wave = threadIdx.x >> 6, lane = threadIdx.x & 63;
  int base, nlim;
  if (GSWZ){
    int g = blockIdx.x & 7;
    base = g * NPG + ((blockIdx.x >> 3) * 4 + wave) * R;
    nlim = g * NPG + NPG;
  } else {
    base = (blockIdx.x * 4 + wave) * R;
    nlim = n;
  }

  if (base < nlim){
    const float4* src4 = (const float4*)(in + (size_t)base * CIN);
    const float4* res4 = resid ? (const float4*)(resid + (size_t)base * CIN) : nullptr;
    float4* side4 = side ? (float4*)(side + (size_t)base * CIN) : nullptr;
    float4* dst4 = (float4*)lds[wave];
    int n4 = min(R, nlim - base) * CIN / 4;
    for (int i = lane; i < R * CIN / 4; i += 64){
      float4 v = (i < n4) ? src4[i] : make_float4(0.f, 0.f, 0.f, 0.f);
      if (FIX){
        v.x = isfinite(v.x) ? v.x : 0.f; v.y = isfinite(v.y) ? v.y : 0.f;
        v.z = isfinite(v.z) ? v.z : 0.f; v.w = isfinite(v.w) ? v.w : 0.f;
      }
      if (BNIN){
        int c0 = (i * 4) & (CIN - 1);
        v.x = elu1(fmaf(v.x, ss[c0 + 0], ss[128 + c0 + 0]));
        v.y = elu1(fmaf(v.y, ss[c0 + 1], ss[128 + c0 + 1]));
        v.z = elu1(fmaf(v.z, ss[c0 + 2], ss[128 + c0 + 2]));
        v.w = elu1(fmaf(v.w, ss[c0 + 3], ss[128 + c0 + 3]));
        if (res4 && i < n4){
          float4 r = res4[i];
          v.x += r.x; v.y += r.y; v.z += r.z; v.w += r.w;
        }
        if (side4 && i < n4) side4[i] = v;
      }
      dst4[i] = v;
    }
  }
  __builtin_amdgcn_wave_barrier();   // wave-local LDS slice: no block barrier

  bool act = (COUT >= 64) || (lane < COUT);
  float acc[CPL][R];
  #pragma unroll
  for (int j = 0; j < CPL; j++)
    #pragma unroll
    for (int r = 0; r < R; r++) acc[j][r] = 0.f;

  if (base < nlim && act){
    const float4* l4 = (const float4*)lds[wave];
    for (int k = 0; k < CIN; k += 4){
      float4 wv[CPL];
      #pragma unroll
      for (int j = 0; j < CPL; j++){
        int c = lane + 64 * j;
        wv[j].x = w[(k + 0) * COUT + c];
        wv[j].y = w[(k + 1) * COUT + c];
        wv[j].z = w[(k + 2) * COUT + c];
        wv[j].w = w[(k + 3) * COUT + c];
      }
      #pragma unroll
      for (int r = 0; r < R; r++){
        float4 a = l4[(r * CIN + k) >> 2];
        #pragma unroll
        for (int j = 0; j < CPL; j++)
          acc[j][r] = fmaf(a.x, wv[j].x, fmaf(a.y, wv[j].y,
                      fmaf(a.z, wv[j].z, fmaf(a.w, wv[j].w, acc[j][r]))));
      }
    }
    float q0[POSW ? CPL : 1], q1[POSW ? CPL : 1], q2[POSW ? CPL : 1];
    if (POSW){
      #pragma unroll
      for (int j = 0; j < CPL; j++){
        int c = lane + 64 * j;
        q0[j] = w3p[c]; q1[j] = w3p[COUT + c]; q2[j] = w3p[2 * COUT + c];
      }
    }
    int nrows = min(R, nlim - base);
    for (int r = 0; r < nrows; r++){
      if (POSW){
        float px = posn[(size_t)(base + r) * 3 + 0];
        float py = posn[(size_t)(base + r) * 3 + 1];
        float pz = posn[(size_t)(base + r) * 3 + 2];
        #pragma unroll
        for (int j = 0; j < CPL; j++)
          acc[j][r] = fmaf(px, q0[j], fmaf(py, q1[j], fmaf(pz, q2[j], acc[j][r])));
      }
      #pragma unroll
      for (int j = 0; j < CPL; j++)
        out[(size_t)(base + r) * COUT + lane + 64 * j] = acc[j][r];
    }
  }

  if (STATS){
    #pragma unroll
    for (int j = 0; j < CPL; j++){
      float s = 0.f, q = 0.f;
      #pragma unroll
      for (int r = 0; r < R; r++){ s += acc[j][r]; q += acc[j][r] * acc[j][r]; }
      if (act){
        int c = threadIdx.x % 64 + 64 * j;
        sred[(2 * wave + 0) * COUT + c] = s;
        sred[(2 * wave + 1) * COUT + c] = q;
      }
    }
    __syncthreads();                 // cross-wave reduction: real barrier
    int c = threadIdx.x;
    if (c < COUT){
      float S = 0.f, Q = 0.f;
      #pragma unroll
      for (int wv = 0; wv < 4; wv++){
        S += sred[(2 * wv + 0) * COUT + c];
        Q += sred[(2 * wv + 1) * COUT + c];
      }
      float* st = stat + (size_t)(blockIdx.x & (NSTRIPE - 1)) * 256;
      atomicAdd(&st[c], S);
      atomicAdd(&st[128 + c], Q);
    }
  }
}

// ---------- FUSED edge aggregation + wg GEMM (+ BN stats) --------------------
// One wave owns 8 dst rows. Phase A: gather-max over each row's edges (same
// loop as the standalone edge kernel: coalesced u16 preload + readlane
// broadcast + 4 indep chains), corr/FIX, stage straight into the wave's LDS
// slice. Phase B: y = staged @ wg with fused stats. Kills the AG round-trip
// between the edge pass and the wg GEMM, and overlaps gather-latency waves
// with FMA-issue waves in one dispatch.
template<int CPL>   // COUT = 64*CPL (1: 64-ch layers, 2: 128-ch L5)
__global__ __launch_bounds__(256) void edge_gemm(
    const float* __restrict__ u, int ushift,
    const unsigned short* __restrict__ col,
    const int* __restrict__ row_start, const float* __restrict__ pos,
    const float* __restrict__ w3, const float* __restrict__ wg,
    float* __restrict__ out, float* __restrict__ stat){
  constexpr int COUT = 64 * CPL;
  constexpr int R = 8;
  __shared__ float lds[4][R * COUT];
  __shared__ float sred[8 * COUT];
  int wave = threadIdx.x >> 6, lane = threadIdx.x & 63;
  int g = blockIdx.x & 7;
  int base = g * NPG + ((blockIdx.x >> 3) * 4 + wave) * R;
  int glim = g * NPG + NPG;
  const float* uu = u + ((size_t)(g * NPG) << ushift) + lane;
  float* dstl = lds[wave];

  // ---- phase A: edge aggregation, staged to LDS ----
  for (int r = 0; r < R; ++r){
    int d = base + r;
    float a0[CPL], a1[CPL], a2[CPL], a3[CPL];
    #pragma unroll
    for (int p = 0; p < CPL; p++){ a0[p] = a1[p] = a2[p] = a3[p] = -INFINITY; }
    if (d < glim){
      int e0 = row_start[d], e1 = row_start[d + 1];
      for (int eb = e0; eb < e1; eb += 64){
        int m = min(64, e1 - eb);
        int sv = ((int)col[eb + min(lane, m - 1)]) << ushift;
        for (int j = 0; j < m; j += 4){
          int j1 = min(j + 1, m - 1), j2 = min(j + 2, m - 1), j3 = min(j + 3, m - 1);
          int s0 = __builtin_amdgcn_readlane(sv, j);
          int s1 = __builtin_amdgcn_readlane(sv, j1);
          int s2 = __builtin_amdgcn_readlane(sv, j2);
          int s3 = __builtin_amdgcn_readlane(sv, j3);
          #pragma unroll
          for (int p = 0; p < CPL; p++){
            a0[p] = fmaxf(a0[p], uu[s0 + 64 * p]);
            a1[p] = fmaxf(a1[p], uu[s1 + 64 * p]);
            a2[p] = fmaxf(a2[p], uu[s2 + 64 * p]);
            a3[p] = fmaxf(a3[p], uu[s3 + 64 * p]);
          }
        }
      }
      float px = pos[d * 3 + 0], py = pos[d * 3 + 1], pz = pos[d * 3 + 2];
      #pragma unroll
      for (int p = 0; p < CPL; p++){
        int c = lane + 64 * p;
        float corr = fmaf(px, w3[c], fmaf(py, w3[COUT + c], pz * w3[2 * COUT + c]));
        float h = fmaxf(fmaxf(a0[p], a1[p]), fmaxf(a2[p], a3[p])) - corr;
        dstl[r * COUT + c] = isfinite(h) ? h : 0.f;
      }
    } else {
      #pragma unroll
      for (int p = 0; p < CPL; p++) dstl[r * COUT + lane + 64 * p] = 0.f;
    }
  }
  __builtin_amdgcn_wave_barrier();   // wave-local staging

  // ---- phase B: y = staged @ wg ----
  float acc[CPL][R];
  #pragma unroll
  for (int j = 0; j < CPL; j++)
    #pragma unroll
    for (int r = 0; r < R; r++) acc[j][r] = 0.f;

  const float4* l4 = (const float4*)dstl;
  for (int k = 0; k < COUT; k += 4){
    float4 wv[CPL];
    #pragma unroll
    for (int j = 0; j < CPL; j++){
      int c = lane + 64 * j;
      wv[j].x = wg[(k + 0) * COUT + c];
      wv[j].y = wg[(k + 1) * COUT + c];
      wv[j].z = wg[(k + 2) * COUT + c];
      wv[j].w = wg[(k + 3) * COUT + c];
    }
    #pragma unroll
    for (int r = 0; r < R; r++){
      float4 a = l4[(r * COUT + k) >> 2];
      #pragma unroll
      for (int j = 0; j < CPL; j++)
        acc[j][r] = fmaf(a.x, wv[j].x, fmaf(a.y, wv[j].y,
                    fmaf(a.z, wv[j].z, fmaf(a.w, wv[j].w, acc[j][r]))));
    }
  }
  int nrows = min(R, glim - base);
  for (int r = 0; r < nrows; r++){
    #pragma unroll
    for (int j = 0; j < CPL; j++)
      out[(size_t)(base + r) * COUT + lane + 64 * j] = acc[j][r];
  }

  // ---- fused BN stats (striped) ----
  #pragma unroll
  for (int j = 0; j < CPL; j++){
    float s = 0.f, q = 0.f;
    #pragma unroll
    for (int r = 0; r < R; r++){ s += acc[j][r]; q += acc[j][r] * acc[j][r]; }
    int c = lane + 64 * j;
    sred[(2 * wave + 0) * COUT + c] = s;
    sred[(2 * wave + 1) * COUT + c] = q;
  }
  __syncthreads();
  int c = threadIdx.x;
  if (c < COUT){
    float S = 0.f, Q = 0.f;
    #pragma unroll
    for (int wv = 0; wv < 4; wv++){
      S += sred[(2 * wv + 0) * COUT + c];
      Q += sred[(2 * wv + 1) * COUT + c];
    }
    float* st = stat + (size_t)(blockIdx.x & (NSTRIPE - 1)) * 256;
    atomicAdd(&st[c], S);
    atomicAdd(&st[128 + c], Q);
  }
}

// ---------- layer-1 node transform: u~[n,16] = x[n]*wl[0,:] + pos[n].wl[1:4,:]
__global__ void node1_kernel(const float* __restrict__ x, const float* __restrict__ pos,
                             const float* __restrict__ wl, float* __restrict__ u){
  int i = blockIdx.x * 256 + threadIdx.x;
  if (i >= N_NODES * 16) return;
  int node = i >> 4, c = i & 15;
  float px = pos[node * 3 + 0], py = pos[node * 3 + 1], pz = pos[node * 3 + 2];
  u[i] = fmaf(x[node], wl[c],
         fmaf(px, wl[16 + c], fmaf(py, wl[32 + c], pz * wl[48 + c])));
}

// ---------- layer-1 edge aggregation: 16 channels, 4 dst nodes per wave ------
__global__ __launch_bounds__(256) void edge_agg16(
    const float* __restrict__ u,
    const unsigned short* __restrict__ col,
    const float* __restrict__ w3,
    const int* __restrict__ row_start, const float* __restrict__ pos,
    float* __restrict__ agg){
  int wave = threadIdx.x >> 6, lane = threadIdx.x & 63;
  int slot = lane >> 4, c = lane & 15;
  int g = blockIdx.x & 7;
  int dloc = (blockIdx.x >> 3) * 16 + wave * 4 + slot;
  int d = g * NPG + dloc;
  bool vd = dloc < NPG;
  int e0 = vd ? row_start[d] : 0;
  int e1 = vd ? row_start[d + 1] : 0;
  int len = e1 - e0;
  int maxlen = max(len, __shfl_xor(len, 16, 64));
  maxlen = max(maxlen, __shfl_xor(maxlen, 32, 64));
  int cap = max(len - 1, 0);
  const float* uu = u + ((size_t)(g * NPG) << 4) + c;
  float acc0 = -INFINITY, acc1 = -INFINITY;
  for (int k = 0; k < maxlen; k += 2){
    int s0 = ((int)col[e0 + min(k, cap)]) << 4;
    int s1 = ((int)col[e0 + min(k + 1, cap)]) << 4;
    float h0 = uu[s0];
    float h1 = uu[s1];
    acc0 = (k < len) ? fmaxf(acc0, h0) : acc0;
    acc1 = (k + 1 < len) ? fmaxf(acc1, h1) : acc1;
  }
  if (vd){
    float w0 = w3[c], w1 = w3[16 + c], w2 = w3[32 + c];
    float px = pos[d * 3 + 0], py = pos[d * 3 + 1], pz = pos[d * 3 + 2];
    float corr = fmaf(px, w0, fmaf(py, w1, pz * w2));
    agg[d * 16 + c] = fmaxf(acc0, acc1) - corr;
  }
}

// one block per channel, one lane per stripe: parallel stripe reduction
__global__ void bn_finalize(const float* __restrict__ stats, const float* __restrict__ g,
                            const float* __restrict__ b, int cout, float invn,
                            float* __restrict__ ss){
  int c = blockIdx.x;
  if (c >= cout) return;
  int l = threadIdx.x;
  float S = stats[l * 256 + c];
  float Q = stats[l * 256 + 128 + c];
  for (int off = 32; off > 0; off >>= 1){
    S += __shfl_down(S, off, 64);
    Q += __shfl_down(Q, off, 64);
  }
  if (l == 0){
    float mean = S * invn;
    float var = fmaxf(Q * invn - mean * mean, 0.f);
    float sc = g[c] * rsqrtf(var + 1e-5f);
    ss[c] = sc;
    ss[128 + c] = b[c] - mean * sc;
  }
}

// ---------- pool5: cluster assignment + counts + pos sums ----------
__global__ void pool5_a(const float* __restrict__ pos, const int* __restrict__ batch,
                        int* __restrict__ clus, int* __restrict__ ccnt,
                        float* __restrict__ psum){
  int i = blockIdx.x * 256 + threadIdx.x;
  if (i >= N_NODES) return;
  int cx = min(max((int)floorf(pos[i * 3 + 0] * 8.f), 0), 7);
  int cy = min(max((int)floorf(pos[i * 3 + 1] * 8.f), 0), 7);
  int cl = batch[i] * 64 + cx * 8 + cy;
  clus[i] = cl;
  atomicAdd(&ccnt[cl], 1);
  atomicAdd(&psum[cl * 3 + 0], pos[i * 3 + 0]);
  atomicAdd(&psum[cl * 3 + 1], pos[i * 3 + 1]);
  atomicAdd(&psum[cl * 3 + 2], pos[i * 3 + 2]);
}

// 512-entry exclusive scan for cluster offsets (single block)
__global__ void cluster_scan(const int* __restrict__ ccnt, int* __restrict__ coff){
  __shared__ int sm[C1];
  int t = threadIdx.x;
  sm[t] = ccnt[t]; __syncthreads();
  for (int off = 1; off < C1; off <<= 1){
    int v = (t >= off) ? sm[t - off] : 0;
    __syncthreads();
    sm[t] += v;
    __syncthreads();
  }
  coff[t + 1] = sm[t];
  if (t == 0) coff[0] = 0;
}

__global__ void cluster_fill(const int* __restrict__ clus, const int* __restrict__ coff,
                             int* __restrict__ ccur, int* __restrict__ nb){
  int i = blockIdx.x * 256 + threadIdx.x;
  if (i >= N_NODES) return;
  int cl = clus[i];
  int p = atomicAdd(&ccur[cl], 1);
  nb[coff[cl] + p] = i;
}

// atomic-free pool5: one block per cluster, register max over its node rows.
__global__ __launch_bounds__(128) void pool5_g(
    const float* __restrict__ y, const float* __restrict__ ss,
    const int* __restrict__ coff, const int* __restrict__ nb,
    const int* __restrict__ ccnt, const float* __restrict__ psum,
    float* __restrict__ hcf, float* __restrict__ posc, int* __restrict__ pf){
  __shared__ int nid[128];
  int d = blockIdx.x, c = threadIdx.x;
  int b0 = coff[d], b1 = coff[d + 1];
  float a0 = -INFINITY, a1 = -INFINITY;
  for (int base = b0; base < b1; base += 128){
    int m = min(128, b1 - base);
    __syncthreads();
    if (c < m) nid[c] = nb[base + c];
    __syncthreads();
    int k = 0;
    for (; k + 2 <= m; k += 2){
      float v0 = y[(size_t)nid[k] * 128 + c];
      float v1 = y[(size_t)nid[k + 1] * 128 + c];
      a0 = fmaxf(a0, v0);
      a1 = fmaxf(a1, v1);
    }
    if (k < m) a0 = fmaxf(a0, y[(size_t)nid[k] * 128 + c]);
  }
  float acc = fmaxf(a0, a1);
  float out = (b1 > b0) ? elu1(fmaf(acc, ss[c], ss[128 + c])) : 0.f;
  hcf[d * 128 + c] = isfinite(out) ? out : 0.f;
  if (c < 3) posc[d * 3 + c] = psum[d * 3 + c] / fmaxf((float)ccnt[d], 1.f);
  if (c == 0) pf[d * 64 + (d & 63)] = 1;   // coarse self-loop
}

// ---------- coarse conv: dedup'd pairs; u2 is u~ (posw folded) ----------
__global__ __launch_bounds__(128) void coarse_conv(
    const float* __restrict__ u2, const float* __restrict__ posc,
    const float* __restrict__ wl, const int* __restrict__ pf,
    const float* __restrict__ wg, float* __restrict__ y2,
    float* __restrict__ stat){
  __shared__ float sagg[128];
  int d = blockIdx.x, c = threadIdx.x;
  int g = d >> 6;
  float acc = -INFINITY;
  for (int j = 0; j < 64; ++j){
    if (pf[d * 64 + j]){
      int s = g * 64 + j;
      acc = fmaxf(acc, u2[s * 128 + c]);
    }
  }
  const float* wb = wl + 128 * 128;
  float w0 = wb[c], w1 = wb[128 + c], w2 = wb[256 + c];
  float px = posc[d * 3 + 0], py = posc[d * 3 + 1], pz = posc[d * 3 + 2];
  float corr = fmaf(px, w0, fmaf(py, w1, pz * w2));
  acc -= corr;                       // self-loop guarantees acc finite
  sagg[c] = isfinite(acc) ? acc : 0.f;
  __syncthreads();
  float y = 0.f;
  for (int k = 0; k < 128; ++k) y = fmaf(sagg[k], wg[k * 128 + c], y);
  y2[d * 128 + c] = y;
  float* st = stat + (size_t)(d & (NSTRIPE - 1)) * 256;
  atomicAdd(&st[c], y);
  atomicAdd(&st[128 + c], y * y);
}

// ---------- pool7: fused BN+ELU(layer-7) + residual(hc) + max-pool ----------
__global__ void pool7(const float* __restrict__ y2, const float* __restrict__ ss,
                      const float* __restrict__ hcf, const float* __restrict__ posc,
                      unsigned* __restrict__ xoe){
  int i = blockIdx.x, c = threadIdx.x;
  int g = i >> 6;
  float v = elu1(fmaf(y2[i * 128 + c], ss[c], ss[128 + c])) + hcf[i * 128 + c];
  int cx = min(max((int)floorf(posc[i * 3 + 0] * 4.f), 0), 3);
  int cy = min(max((int)floorf(posc[i * 3 + 1] * 4.f), 0), 3);
  int cl2 = g * 16 + cx * 4 + cy;
  atomicMax(&xoe[cl2 * 128 + c], fenc(v));
}

// ---------- final FC: (8,2048) @ (2048,10) ----------
__global__ void fc_kernel(const unsigned* __restrict__ xoe, const float* __restrict__ wfc,
                          float* __restrict__ out){
  int o = blockIdx.x;
  int b = o / 10, cls = o % 10;
  int lane = threadIdx.x;
  float s = 0.f;
  for (int k = lane; k < 2048; k += 64){
    float v = fdec(xoe[b * 2048 + k]);
    v = isfinite(v) ? v : 0.f;
    s = fmaf(v, wfc[k * 10 + cls], s);
  }
  for (int off = 32; off > 0; off >>= 1) s += __shfl_down(s, off, 64);
  if (lane == 0) out[o] = s;
}

// ---------- host ----------
extern "C" void kernel_launch(void* const* d_in, const int* in_sizes, int n_in,
                              void* d_out, int out_size, void* d_ws, size_t ws_size,
                              hipStream_t stream){
  (void)in_sizes; (void)n_in; (void)out_size; (void)ws_size;
  const float* X   = (const float*)d_in[0];
  const float* POS = (const float*)d_in[1];
  const int*   SRC = (const int*)d_in[2];
  const int*   DST = (const int*)d_in[3];
  const int*   BAT = (const int*)d_in[4];
  const float* WL[7]; const float* WG[7]; const float* GG[7]; const float* BB[7];
  for (int i = 0; i < 7; i++){
    WL[i] = (const float*)d_in[5 + 4 * i];
    WG[i] = (const float*)d_in[6 + 4 * i];
    GG[i] = (const float*)d_in[7 + 4 * i];
    BB[i] = (const float*)d_in[8 + 4 * i];
  }
  const float* WFC = (const float*)d_in[33];
  float* OUT = (float*)d_out;

  // workspace layout (floats)
  float* wsf = (float*)d_ws;
  size_t o = 0;
  auto alloc = [&](size_t nf){ float* p = wsf + o; o += nf; return p; };
  float* F1   = alloc((size_t)N_NODES * 64);    // h2 (layer-2 activation, resid for L5)
  float* U    = alloc((size_t)N_NODES * 128);
  float* AG   = alloc((size_t)N_NODES * 128);
  float* HCF  = alloc(C1 * 128);
  float* POSC = alloc(2048);
  float* U2   = alloc(C1 * 128);
  float* Y2   = alloc(C1 * 128);
  float* SS   = alloc(9 * 256);
  unsigned short* COL  = (unsigned short*)alloc(E_TOT / 2 + 64);  // u16 src packets
  unsigned short* ERNK = (unsigned short*)alloc(E_TOT / 2 + 64);  // u16 edge ranks
  int* ROWS = (int*)alloc(N_NODES + 8);
  int* PART = (int*)alloc(256);
  int* CLUS = (int*)alloc(N_NODES);
  int* NB   = (int*)alloc(N_NODES);             // cluster node buckets
  int* COFF = (int*)alloc(C1 + 8);
  // ---- zero zone ----
  int* ZZ = (int*)(wsf + o);
  int*      DEG  = (int*)alloc(N_NODES);        // accumulated by count_deg merge
  float*    STAT = alloc((size_t)9 * NSTRIPE * 256);
  int*      CCNT = (int*)alloc(512);
  int*      CCUR = (int*)alloc(512);
  float*    PSUM = alloc(2048);
  int*      PF   = (int*)alloc(C1 * 64);
  unsigned* XOE  = (unsigned*)alloc(128 * 128);
  int zz_n = (int)((int*)(wsf + o) - ZZ);

  zero_kernel<<<cdiv(zz_n, 256), 256, 0, stream>>>(ZZ, zz_n);

  // clusters first (needed by fused fill_csr pair flags)
  pool5_a<<<cdiv(N_NODES, 256), 256, 0, stream>>>(POS, BAT, CLUS, CCNT, PSUM);
  cluster_scan<<<1, C1, 0, stream>>>(CCNT, COFF);
  cluster_fill<<<cdiv(N_NODES, 256), 256, 0, stream>>>(CLUS, COFF, CCUR, NB);

  // CSR build (LDS chunk count + contiguous merge -> scan -> atomic-free fill)
  count_deg<<<8 * NCHUNK, 1024, 0, stream>>>(DST, DEG, ERNK);
  scan1<<<NB_SCAN, 256, 0, stream>>>(DEG, ROWS, PART);
  scan2<<<1, 1, 0, stream>>>(PART);
  scan3<<<cdiv(N_NODES, 256), 256, 0, stream>>>(ROWS, PART);
  dim3 gF(8 * cdiv(EPG_TOT, 256));
  fill_csr<<<gF, 256, 0, stream>>>(SRC, DST, CLUS, ERNK, ROWS, COL, PF);

  dim3 gE16(8 * cdiv(NPG, 16));
  dim3 gT(8 * cdiv(NPG, 32)), bT(256);   // R=8 swizzled grid: 391 blocks/graph
  dim3 gC(cdiv(C1, 32));                 // coarse R=8 grid

  const size_t LSTAT = (size_t)NSTRIPE * 256;
  const float invN = 1.f / N_NODES;
  auto fin = [&](int li, int cout, float invn){
    bn_finalize<<<128, 64, 0, stream>>>(STAT + li * LSTAT, GG[li], BB[li], cout, invn, SS + li * 256);
  };

  // ---- layer 1: 1 -> 16 ----
  node1_kernel<<<cdiv(N_NODES * 16, 256), 256, 0, stream>>>(X, POS, WL[0], U);
  edge_agg16<<<gE16, bT, 0, stream>>>(U, COL, WL[0] + 16, ROWS, POS, AG);
  gemm_tile<8, 16, 16, true, true, false, false, true><<<gT, bT, 0, stream>>>(
      AG, WG[0], nullptr, nullptr, nullptr, nullptr, nullptr, AG, STAT + 0 * LSTAT, N_NODES);
  fin(0, 16, invN);

  // ---- layer 2: 16 -> 64 (node gemm, then FUSED edge+wg gemm) ----
  gemm_tile<8, 16, 64, false, false, true, true, true><<<gT, bT, 0, stream>>>(
      AG, WL[1], SS + 0 * 256, nullptr, nullptr, POS, WL[1] + 16 * 64, U, nullptr, N_NODES);
  edge_gemm<1><<<gT, bT, 0, stream>>>(U, 6, COL, ROWS, POS, WL[1] + 16 * 64, WG[1], AG, STAT + 1 * LSTAT);
  fin(1, 64, invN);

  // ---- layer 3: 64 -> 64  (side-writes h2 -> F1 for the L5 residual) ----
  gemm_tile<8, 64, 64, false, false, true, true, true><<<gT, bT, 0, stream>>>(
      AG, WL[2], SS + 1 * 256, nullptr, F1, POS, WL[2] + 64 * 64, U, nullptr, N_NODES);
  edge_gemm<1><<<gT, bT, 0, stream>>>(U, 6, COL, ROWS, POS, WL[2] + 64 * 64, WG[2], AG, STAT + 2 * LSTAT);
  fin(2, 64, invN);

  // ---- layer 4: 64 -> 64 ----
  gemm_tile<8, 64, 64, false, false, true, true, true><<<gT, bT, 0, stream>>>(
      AG, WL[3], SS + 2 * 256, nullptr, nullptr, POS, WL[3] + 64 * 64, U, nullptr, N_NODES);
  edge_gemm<1><<<gT, bT, 0, stream>>>(U, 6, COL, ROWS, POS, WL[3] + 64 * 64, WG[3], AG, STAT + 3 * LSTAT);
  fin(3, 64, invN);

  // ---- layer 5: 64 -> 128  (input = act4 + h2 residual; fused 128-ch) ----
  gemm_tile<8, 64, 128, false, false, true, true, true><<<gT, bT, 0, stream>>>(
      AG, WL[4], SS + 3 * 256, F1, nullptr, POS, WL[4] + 64 * 128, U, nullptr, N_NODES);
  edge_gemm<2><<<gT, bT, 0, stream>>>(U, 7, COL, ROWS, POS, WL[4] + 64 * 128, WG[4], AG, STAT + 4 * LSTAT);
  fin(4, 128, invN);

  // pool5: atomic-free cluster max (act5 fused after raw max)
  pool5_g<<<C1, 128, 0, stream>>>(AG, SS + 4 * 256, COFF, NB, CCNT, PSUM, HCF, POSC, PF);

  // ---- coarse layer 6 (u~ = HCF @ wl + posc @ w3, posw folded) ----
  gemm_tile<8, 128, 128, false, false, false, true, false><<<gC, bT, 0, stream>>>(
      HCF, WL[5], nullptr, nullptr, nullptr, POSC, WL[5] + 128 * 128, U2, nullptr, C1);
  coarse_conv<<<C1, 128, 0, stream>>>(U2, POSC, WL[5], PF, WG[5], Y2, STAT + 5 * LSTAT);
  fin(5, 128, 1.f / C1);

  // ---- coarse layer 7 (consumes act6 inline) ----
  gemm_tile<8, 128, 128, false, false, true, true, false><<<gC, bT, 0, stream>>>(
      Y2, WL[6], SS + 5 * 256, nullptr, nullptr, POSC, WL[6] + 128 * 128, U2, nullptr, C1);
  coarse_conv<<<C1, 128, 0, stream>>>(U2, POSC, WL[6], PF, WG[6], Y2, STAT + 6 * LSTAT);
  fin(6, 128, 1.f / C1);

  // pool7: act7 + hc residual applied inline
  pool7<<<C1, 128, 0, stream>>>(Y2, SS + 6 * 256, HCF, POSC, XOE);
  fc_kernel<<<80, 64, 0, stream>>>(XOE, WFC, OUT);
}

// Round 24
// 919.642 us; speedup vs baseline: 1.0481x; 1.0481x over previous
//
#include <hip/hip_runtime.h>
#include <math.h>

#define N_NODES 100000
#define NPG     12500
#define EPG     200000
#define EPG_TOT 212500   // per-graph edges incl self-loops
#define E_TOT   1700000
#define C1      512
#define NB_SCAN 98   // ceil(100000/1024)
#define NSTRIPE 64   // stats striping
#define NCHUNK  8    // count_deg chunks per graph
#define CHUNK   26563  // ceil(EPG_TOT / NCHUNK)

static inline int cdiv(int a, int b){ return (a + b - 1) / b; }

// ---------- ordered-float encoding for atomic max (pool7 only) ----------
__device__ __forceinline__ unsigned fenc(float f){
  unsigned u = __float_as_uint(f);
  return (u >> 31) ? ~u : (u | 0x80000000u);
}
__device__ __forceinline__ float fdec(unsigned e){
  return (e & 0x80000000u) ? __uint_as_float(e ^ 0x80000000u) : __uint_as_float(~e);
}

__device__ __forceinline__ float elu1(float v){ return v > 0.f ? v : expm1f(v); }

// ---------- utility ----------
__global__ void zero_kernel(int* __restrict__ p, int n){
  int i = blockIdx.x * 256 + threadIdx.x;
  if (i < n) p[i] = 0;
}

// ---------- degree count + edge ranks: LDS counting, 8 chunks/graph ----------
// R20: scattered GLOBAL per-edge atomics cost ~32B HBM writeback each (53MB).
// R21: 8-block LDS version starved parallelism. This: 64 blocks, LDS chunk
// counts (local ranks), merge via contiguous global atomics (block base),
// then add base to local ranks. Row order is a permutation -> fine for max.
__global__ __launch_bounds__(1024) void count_deg(
    const int* __restrict__ dst, int* __restrict__ deg,
    unsigned short* __restrict__ ernk){
  __shared__ int ldeg[NPG];
  __shared__ int lbase[NPG];
  int g = blockIdx.x & 7;
  int chunk = blockIdx.x >> 3;
  int t = threadIdx.x;
  for (int j = t; j < NPG; j += 1024) ldeg[j] = 0;
  __syncthreads();
  int i0 = chunk * CHUNK;
  int i1 = min(i0 + CHUNK, EPG_TOT);
  for (int idx = i0 + t; idx < i1; idx += 1024){
    int dl = (idx < EPG) ? (dst[g * EPG + idx] - g * NPG) : (idx - EPG);
    int p = atomicAdd(&ldeg[dl], 1);
    ernk[(size_t)g * EPG_TOT + idx] = (unsigned short)p;   // local rank
  }
  __syncthreads();
  for (int j = t; j < NPG; j += 1024){
    int cnt = ldeg[j];
    lbase[j] = cnt ? atomicAdd(&deg[g * NPG + j], cnt) : 0;  // contiguous atomics
  }
  __syncthreads();
  for (int idx = i0 + t; idx < i1; idx += 1024){
    int dl = (idx < EPG) ? (dst[g * EPG + idx] - g * NPG) : (idx - EPG);
    ernk[(size_t)g * EPG_TOT + idx] += (unsigned short)lbase[dl];
  }
}

__global__ void scan1(const int* __restrict__ deg, int* __restrict__ row_start,
                      int* __restrict__ partials){
  __shared__ int sm[256];
  int t = threadIdx.x, b = blockIdx.x;
  int base = b * 1024 + t * 4;
  int d0 = (base + 0 < N_NODES) ? deg[base + 0] : 0;
  int d1 = (base + 1 < N_NODES) ? deg[base + 1] : 0;
  int d2 = (base + 2 < N_NODES) ? deg[base + 2] : 0;
  int d3 = (base + 3 < N_NODES) ? deg[base + 3] : 0;
  int s = d0 + d1 + d2 + d3;
  sm[t] = s; __syncthreads();
  for (int off = 1; off < 256; off <<= 1){
    int v = (t >= off) ? sm[t - off] : 0;
    __syncthreads();
    sm[t] += v;
    __syncthreads();
  }
  int excl = sm[t] - s;
  if (base + 0 < N_NODES) row_start[base + 0] = excl;
  if (base + 1 < N_NODES) row_start[base + 1] = excl + d0;
  if (base + 2 < N_NODES) row_start[base + 2] = excl + d0 + d1;
  if (base + 3 < N_NODES) row_start[base + 3] = excl + d0 + d1 + d2;
  if (t == 255) partials[b] = sm[255];
}

__global__ void scan2(int* __restrict__ partials){
  if (threadIdx.x == 0 && blockIdx.x == 0){
    int acc = 0;
    for (int i = 0; i < NB_SCAN; i++){ int v = partials[i]; partials[i] = acc; acc += v; }
  }
}

__global__ void scan3(int* __restrict__ row_start, const int* __restrict__ partials){
  int i = blockIdx.x * 256 + threadIdx.x;
  if (i < N_NODES) row_start[i] += partials[i >> 10];
  if (i == 0) row_start[N_NODES] = E_TOT;
}

// fill CSR: atomic-free (rank precomputed in count_deg); u16 graph-local src.
__global__ void fill_csr(const int* __restrict__ src, const int* __restrict__ dst,
                         const int* __restrict__ clus, const unsigned short* __restrict__ ernk,
                         const int* __restrict__ row_start,
                         unsigned short* __restrict__ col, int* __restrict__ pf){
  int g = blockIdx.x & 7;
  int idx = (blockIdx.x >> 3) * 256 + threadIdx.x;
  if (idx >= EPG_TOT) return;
  int s, d;
  if (idx < EPG){ int e = g * EPG + idx; s = src[e]; d = dst[e]; }
  else { s = d = g * NPG + idx - EPG; }    // self-loop segment
  int p = ernk[(size_t)g * EPG_TOT + idx];
  col[row_start[d] + p] = (unsigned short)(s - g * NPG);
  pf[clus[d] * 64 + (clus[s] & 63)] = 1;   // fused coarse pair-dedup
}

// ---------- tiled GEMM: out[n,COUT] = stage(in[n,CIN]) @ w (+ pos @ w3) -----
// Weight access w[(k+i)*COUT + c] is lane-coalesced and optimal (R17 transposed
// layout was 2x slower). R=8: 20KB LDS keeps occupancy (R=16 measured worse).
// R22: fusing edge-agg into this kernel broke gather L2 locality (FETCH
// 35->187MB) - keep edge pass as its own max-parallelism dispatch.
template<int R, int CIN, int COUT, bool FIX, bool STATS, bool BNIN, bool POSW, bool GSWZ>
__global__ __launch_bounds__(256) void gemm_tile(
    const float* __restrict__ in, const float* __restrict__ w,
    const float* __restrict__ ss, const float* __restrict__ resid,
    float* __restrict__ side, const float* __restrict__ posn,
    const float* __restrict__ w3p, float* __restrict__ out,
    float* __restrict__ stat, int n){
  constexpr int CPL = (COUT + 63) / 64;
  __shared__ float lds[4][R * CIN];
  __shared__ float sred[STATS ? 8 * COUT : 1];
  int wave = threadIdx.x >> 6, lane = threadIdx.x & 63;
  int base, nlim;
  if (GSWZ){
    int g = blockIdx.x & 7;
    base = g * NPG + ((blockIdx.x >> 3) * 4 + wave) * R;
    nlim = g * NPG + NPG;
  } else {
    base = (blockIdx.x * 4 + wave) * R;
    nlim = n;
  }

  if (base < nlim){
    const float4* src4 = (const float4*)(in + (size_t)base * CIN);
    const float4* res4 = resid ? (const float4*)(resid + (size_t)base * CIN) : nullptr;
    float4* side4 = side ? (float4*)(side + (size_t)base * CIN) : nullptr;
    float4* dst4 = (float4*)lds[wave];
    int n4 = min(R, nlim - base) * CIN / 4;
    for (int i = lane; i < R * CIN / 4; i += 64){
      float4 v = (i < n4) ? src4[i] : make_float4(0.f, 0.f, 0.f, 0.f);
      if (FIX){
        v.x = isfinite(v.x) ? v.x : 0.f; v.y = isfinite(v.y) ? v.y : 0.f;
        v.z = isfinite(v.z) ? v.z : 0.f; v.w = isfinite(v.w) ? v.w : 0.f;
      }
      if (BNIN){
        int c0 = (i * 4) & (CIN - 1);
        v.x = elu1(fmaf(v.x, ss[c0 + 0], ss[128 + c0 + 0]));
        v.y = elu1(fmaf(v.y, ss[c0 + 1], ss[128 + c0 + 1]));
        v.z = elu1(fmaf(v.z, ss[c0 + 2], ss[128 + c0 + 2]));
        v.w = elu1(fmaf(v.w, ss[c0 + 3], ss[128 + c0 + 3]));
        if (res4 && i < n4){
          float4 r = res4[i];
          v.x += r.x; v.y += r.y; v.z += r.z; v.w += r.w;
        }
        if (side4 && i < n4) side4[i] = v;
      }
      dst4[i] = v;
    }
  }
  __builtin_amdgcn_wave_barrier();   // wave-local LDS slice: no block barrier

  bool act = (COUT >= 64) || (lane < COUT);
  float acc[CPL][R];
  #pragma unroll
  for (int j = 0; j < CPL; j++)
    #pragma unroll
    for (int r = 0; r < R; r++) acc[j][r] = 0.f;

  if (base < nlim && act){
    const float4* l4 = (const float4*)lds[wave];
    for (int k = 0; k < CIN; k += 4){
      float4 wv[CPL];
      #pragma unroll
      for (int j = 0; j < CPL; j++){
        int c = lane + 64 * j;
        wv[j].x = w[(k + 0) * COUT + c];
        wv[j].y = w[(k + 1) * COUT + c];
        wv[j].z = w[(k + 2) * COUT + c];
        wv[j].w = w[(k + 3) * COUT + c];
      }
      #pragma unroll
      for (int r = 0; r < R; r++){
        float4 a = l4[(r * CIN + k) >> 2];
        #pragma unroll
        for (int j = 0; j < CPL; j++)
          acc[j][r] = fmaf(a.x, wv[j].x, fmaf(a.y, wv[j].y,
                      fmaf(a.z, wv[j].z, fmaf(a.w, wv[j].w, acc[j][r]))));
      }
    }
    float q0[POSW ? CPL : 1], q1[POSW ? CPL : 1], q2[POSW ? CPL : 1];
    if (POSW){
      #pragma unroll
      for (int j = 0; j < CPL; j++){
        int c = lane + 64 * j;
        q0[j] = w3p[c]; q1[j] = w3p[COUT + c]; q2[j] = w3p[2 * COUT + c];
      }
    }
    int nrows = min(R, nlim - base);
    for (int r = 0; r < nrows; r++){
      if (POSW){
        float px = posn[(size_t)(base + r) * 3 + 0];
        float py = posn[(size_t)(base + r) * 3 + 1];
        float pz = posn[(size_t)(base + r) * 3 + 2];
        #pragma unroll
        for (int j = 0; j < CPL; j++)
          acc[j][r] = fmaf(px, q0[j], fmaf(py, q1[j], fmaf(pz, q2[j], acc[j][r])));
      }
      #pragma unroll
      for (int j = 0; j < CPL; j++)
        out[(size_t)(base + r) * COUT + lane + 64 * j] = acc[j][r];
    }
  }

  if (STATS){
    #pragma unroll
    for (int j = 0; j < CPL; j++){
      float s = 0.f, q = 0.f;
      #pragma unroll
      for (int r = 0; r < R; r++){ s += acc[j][r]; q += acc[j][r] * acc[j][r]; }
      if (act){
        int c = lane + 64 * j;
        sred[(2 * wave + 0) * COUT + c] = s;
        sred[(2 * wave + 1) * COUT + c] = q;
      }
    }
    __syncthreads();                 // cross-wave reduction: real barrier
    int c = threadIdx.x;
    if (c < COUT){
      float S = 0.f, Q = 0.f;
      #pragma unroll
      for (int wv = 0; wv < 4; wv++){
        S += sred[(2 * wv + 0) * COUT + c];
        Q += sred[(2 * wv + 1) * COUT + c];
      }
      float* st = stat + (size_t)(blockIdx.x & (NSTRIPE - 1)) * 256;
      atomicAdd(&st[c], S);
      atomicAdd(&st[128 + c], Q);
    }
  }
}

// ---------- layer-1 node transform: u~[n,16] = x[n]*wl[0,:] + pos[n].wl[1:4,:]
__global__ void node1_kernel(const float* __restrict__ x, const float* __restrict__ pos,
                             const float* __restrict__ wl, float* __restrict__ u){
  int i = blockIdx.x * 256 + threadIdx.x;
  if (i >= N_NODES * 16) return;
  int node = i >> 4, c = i & 15;
  float px = pos[node * 3 + 0], py = pos[node * 3 + 1], pz = pos[node * 3 + 2];
  u[i] = fmaf(x[node], wl[c],
         fmaf(px, wl[16 + c], fmaf(py, wl[32 + c], pz * wl[48 + c])));
}

// ---------- edge aggregation: gather-max of u~ + per-dst correction ----------
// CPL channels-per-lane (1: 64-ch layers, 2: 128-ch L5 in ONE pass).
// Index broadcast uses v_readlane (wave-uniform j) instead of ds_bpermute.
template<int CPL>
__global__ __launch_bounds__(256) void edge_aggN(
    const float* __restrict__ u, int ushift,
    const unsigned short* __restrict__ col,
    const float* __restrict__ w3, int cout,
    const int* __restrict__ row_start, const float* __restrict__ pos,
    float* __restrict__ agg){
  int wave = threadIdx.x >> 6, lane = threadIdx.x & 63;
  int g = blockIdx.x & 7;
  int d = g * NPG + (blockIdx.x >> 3) * 4 + wave;
  const float* uu = u + ((size_t)(g * NPG) << ushift) + lane;
  int e0 = row_start[d], e1 = row_start[d + 1];
  float a0[CPL], a1[CPL], a2[CPL], a3[CPL];
  #pragma unroll
  for (int p = 0; p < CPL; p++){ a0[p] = a1[p] = a2[p] = a3[p] = -INFINITY; }
  for (int eb = e0; eb < e1; eb += 64){
    int m = min(64, e1 - eb);
    int sv = ((int)col[eb + min(lane, m - 1)]) << ushift;   // coalesced u16 preload
    for (int j = 0; j < m; j += 4){
      int j1 = min(j + 1, m - 1), j2 = min(j + 2, m - 1), j3 = min(j + 3, m - 1);
      int s0 = __builtin_amdgcn_readlane(sv, j);    // scalar broadcast (uniform j)
      int s1 = __builtin_amdgcn_readlane(sv, j1);
      int s2 = __builtin_amdgcn_readlane(sv, j2);
      int s3 = __builtin_amdgcn_readlane(sv, j3);
      #pragma unroll
      for (int p = 0; p < CPL; p++){
        a0[p] = fmaxf(a0[p], uu[s0 + 64 * p]);
        a1[p] = fmaxf(a1[p], uu[s1 + 64 * p]);
        a2[p] = fmaxf(a2[p], uu[s2 + 64 * p]);
        a3[p] = fmaxf(a3[p], uu[s3 + 64 * p]);
      }
    }
  }
  float px = pos[d * 3 + 0], py = pos[d * 3 + 1], pz = pos[d * 3 + 2];
  #pragma unroll
  for (int p = 0; p < CPL; p++){
    int c = lane + 64 * p;
    float w0 = w3[c], w1 = w3[cout + c], w2 = w3[2 * cout + c];
    float corr = fmaf(px, w0, fmaf(py, w1, pz * w2));
    agg[(size_t)d * cout + c] = fmaxf(fmaxf(a0[p], a1[p]), fmaxf(a2[p], a3[p])) - corr;
  }
}

// ---------- layer-1 edge aggregation: 16 channels, 4 dst nodes per wave ------
__global__ __launch_bounds__(256) void edge_agg16(
    const float* __restrict__ u,
    const unsigned short* __restrict__ col,
    const float* __restrict__ w3,
    const int* __restrict__ row_start, const float* __restrict__ pos,
    float* __restrict__ agg){
  int wave = threadIdx.x >> 6, lane = threadIdx.x & 63;
  int slot = lane >> 4, c = lane & 15;
  int g = blockIdx.x & 7;
  int dloc = (blockIdx.x >> 3) * 16 + wave * 4 + slot;
  int d = g * NPG + dloc;
  bool vd = dloc < NPG;
  int e0 = vd ? row_start[d] : 0;
  int e1 = vd ? row_start[d + 1] : 0;
  int len = e1 - e0;
  int maxlen = max(len, __shfl_xor(len, 16, 64));
  maxlen = max(maxlen, __shfl_xor(maxlen, 32, 64));
  int cap = max(len - 1, 0);
  const float* uu = u + ((size_t)(g * NPG) << 4) + c;
  float acc0 = -INFINITY, acc1 = -INFINITY;
  for (int k = 0; k < maxlen; k += 2){
    int s0 = ((int)col[e0 + min(k, cap)]) << 4;
    int s1 = ((int)col[e0 + min(k + 1, cap)]) << 4;
    float h0 = uu[s0];
    float h1 = uu[s1];
    acc0 = (k < len) ? fmaxf(acc0, h0) : acc0;
    acc1 = (k + 1 < len) ? fmaxf(acc1, h1) : acc1;
  }
  if (vd){
    float w0 = w3[c], w1 = w3[16 + c], w2 = w3[32 + c];
    float px = pos[d * 3 + 0], py = pos[d * 3 + 1], pz = pos[d * 3 + 2];
    float corr = fmaf(px, w0, fmaf(py, w1, pz * w2));
    agg[d * 16 + c] = fmaxf(acc0, acc1) - corr;
  }
}

// one block per channel, one lane per stripe: parallel stripe reduction
__global__ void bn_finalize(const float* __restrict__ stats, const float* __restrict__ g,
                            const float* __restrict__ b, int cout, float invn,
                            float* __restrict__ ss){
  int c = blockIdx.x;
  if (c >= cout) return;
  int l = threadIdx.x;
  float S = stats[l * 256 + c];
  float Q = stats[l * 256 + 128 + c];
  for (int off = 32; off > 0; off >>= 1){
    S += __shfl_down(S, off, 64);
    Q += __shfl_down(Q, off, 64);
  }
  if (l == 0){
    float mean = S * invn;
    float var = fmaxf(Q * invn - mean * mean, 0.f);
    float sc = g[c] * rsqrtf(var + 1e-5f);
    ss[c] = sc;
    ss[128 + c] = b[c] - mean * sc;
  }
}

// ---------- pool5: cluster assignment + counts + pos sums ----------
__global__ void pool5_a(const float* __restrict__ pos, const int* __restrict__ batch,
                        int* __restrict__ clus, int* __restrict__ ccnt,
                        float* __restrict__ psum){
  int i = blockIdx.x * 256 + threadIdx.x;
  if (i >= N_NODES) return;
  int cx = min(max((int)floorf(pos[i * 3 + 0] * 8.f), 0), 7);
  int cy = min(max((int)floorf(pos[i * 3 + 1] * 8.f), 0), 7);
  int cl = batch[i] * 64 + cx * 8 + cy;
  clus[i] = cl;
  atomicAdd(&ccnt[cl], 1);
  atomicAdd(&psum[cl * 3 + 0], pos[i * 3 + 0]);
  atomicAdd(&psum[cl * 3 + 1], pos[i * 3 + 1]);
  atomicAdd(&psum[cl * 3 + 2], pos[i * 3 + 2]);
}

// 512-entry exclusive scan for cluster offsets (single block)
__global__ void cluster_scan(const int* __restrict__ ccnt, int* __restrict__ coff){
  __shared__ int sm[C1];
  int t = threadIdx.x;
  sm[t] = ccnt[t]; __syncthreads();
  for (int off = 1; off < C1; off <<= 1){
    int v = (t >= off) ? sm[t - off] : 0;
    __syncthreads();
    sm[t] += v;
    __syncthreads();
  }
  coff[t + 1] = sm[t];
  if (t == 0) coff[0] = 0;
}

__global__ void cluster_fill(const int* __restrict__ clus, const int* __restrict__ coff,
                             int* __restrict__ ccur, int* __restrict__ nb){
  int i = blockIdx.x * 256 + threadIdx.x;
  if (i >= N_NODES) return;
  int cl = clus[i];
  int p = atomicAdd(&ccur[cl], 1);
  nb[coff[cl] + p] = i;
}

// atomic-free pool5: one block per cluster, register max over its node rows.
__global__ __launch_bounds__(128) void pool5_g(
    const float* __restrict__ y, const float* __restrict__ ss,
    const int* __restrict__ coff, const int* __restrict__ nb,
    const int* __restrict__ ccnt, const float* __restrict__ psum,
    float* __restrict__ hcf, float* __restrict__ posc, int* __restrict__ pf){
  __shared__ int nid[128];
  int d = blockIdx.x, c = threadIdx.x;
  int b0 = coff[d], b1 = coff[d + 1];
  float a0 = -INFINITY, a1 = -INFINITY;
  for (int base = b0; base < b1; base += 128){
    int m = min(128, b1 - base);
    __syncthreads();
    if (c < m) nid[c] = nb[base + c];
    __syncthreads();
    int k = 0;
    for (; k + 2 <= m; k += 2){
      float v0 = y[(size_t)nid[k] * 128 + c];
      float v1 = y[(size_t)nid[k + 1] * 128 + c];
      a0 = fmaxf(a0, v0);
      a1 = fmaxf(a1, v1);
    }
    if (k < m) a0 = fmaxf(a0, y[(size_t)nid[k] * 128 + c]);
  }
  float acc = fmaxf(a0, a1);
  float out = (b1 > b0) ? elu1(fmaf(acc, ss[c], ss[128 + c])) : 0.f;
  hcf[d * 128 + c] = isfinite(out) ? out : 0.f;
  if (c < 3) posc[d * 3 + c] = psum[d * 3 + c] / fmaxf((float)ccnt[d], 1.f);
  if (c == 0) pf[d * 64 + (d & 63)] = 1;   // coarse self-loop
}

// ---------- coarse conv: dedup'd pairs; u2 is u~ (posw folded) ----------
__global__ __launch_bounds__(128) void coarse_conv(
    const float* __restrict__ u2, const float* __restrict__ posc,
    const float* __restrict__ wl, const int* __restrict__ pf,
    const float* __restrict__ wg, float* __restrict__ y2,
    float* __restrict__ stat){
  __shared__ float sagg[128];
  int d = blockIdx.x, c = threadIdx.x;
  int g = d >> 6;
  float acc = -INFINITY;
  for (int j = 0; j < 64; ++j){
    if (pf[d * 64 + j]){
      int s = g * 64 + j;
      acc = fmaxf(acc, u2[s * 128 + c]);
    }
  }
  const float* wb = wl + 128 * 128;
  float w0 = wb[c], w1 = wb[128 + c], w2 = wb[256 + c];
  float px = posc[d * 3 + 0], py = posc[d * 3 + 1], pz = posc[d * 3 + 2];
  float corr = fmaf(px, w0, fmaf(py, w1, pz * w2));
  acc -= corr;                       // self-loop guarantees acc finite
  sagg[c] = isfinite(acc) ? acc : 0.f;
  __syncthreads();
  float y = 0.f;
  for (int k = 0; k < 128; ++k) y = fmaf(sagg[k], wg[k * 128 + c], y);
  y2[d * 128 + c] = y;
  float* st = stat + (size_t)(d & (NSTRIPE - 1)) * 256;
  atomicAdd(&st[c], y);
  atomicAdd(&st[128 + c], y * y);
}

// ---------- pool7: fused BN+ELU(layer-7) + residual(hc) + max-pool ----------
__global__ void pool7(const float* __restrict__ y2, const float* __restrict__ ss,
                      const float* __restrict__ hcf, const float* __restrict__ posc,
                      unsigned* __restrict__ xoe){
  int i = blockIdx.x, c = threadIdx.x;
  int g = i >> 6;
  float v = elu1(fmaf(y2[i * 128 + c], ss[c], ss[128 + c])) + hcf[i * 128 + c];
  int cx = min(max((int)floorf(posc[i * 3 + 0] * 4.f), 0), 3);
  int cy = min(max((int)floorf(posc[i * 3 + 1] * 4.f), 0), 3);
  int cl2 = g * 16 + cx * 4 + cy;
  atomicMax(&xoe[cl2 * 128 + c], fenc(v));
}

// ---------- final FC: (8,2048) @ (2048,10) ----------
__global__ void fc_kernel(const unsigned* __restrict__ xoe, const float* __restrict__ wfc,
                          float* __restrict__ out){
  int o = blockIdx.x;
  int b = o / 10, cls = o % 10;
  int lane = threadIdx.x;
  float s = 0.f;
  for (int k = lane; k < 2048; k += 64){
    float v = fdec(xoe[b * 2048 + k]);
    v = isfinite(v) ? v : 0.f;
    s = fmaf(v, wfc[k * 10 + cls], s);
  }
  for (int off = 32; off > 0; off >>= 1) s += __shfl_down(s, off, 64);
  if (lane == 0) out[o] = s;
}

// ---------- host ----------
extern "C" void kernel_launch(void* const* d_in, const int* in_sizes, int n_in,
                              void* d_out, int out_size, void* d_ws, size_t ws_size,
                              hipStream_t stream){
  (void)in_sizes; (void)n_in; (void)out_size; (void)ws_size;
  const float* X   = (const float*)d_in[0];
  const float* POS = (const float*)d_in[1];
  const int*   SRC = (const int*)d_in[2];
  const int*   DST = (const int*)d_in[3];
  const int*   BAT = (const int*)d_in[4];
  const float* WL[7]; const float* WG[7]; const float* GG[7]; const float* BB[7];
  for (int i = 0; i < 7; i++){
    WL[i] = (const float*)d_in[5 + 4 * i];
    WG[i] = (const float*)d_in[6 + 4 * i];
    GG[i] = (const float*)d_in[7 + 4 * i];
    BB[i] = (const float*)d_in[8 + 4 * i];
  }
  const float* WFC = (const float*)d_in[33];
  float* OUT = (float*)d_out;

  // workspace layout (floats)
  float* wsf = (float*)d_ws;
  size_t o = 0;
  auto alloc = [&](size_t nf){ float* p = wsf + o; o += nf; return p; };
  float* F1   = alloc((size_t)N_NODES * 64);    // h2 (layer-2 activation, resid for L5)
  float* U    = alloc((size_t)N_NODES * 128);
  float* AG   = alloc((size_t)N_NODES * 128);
  float* HCF  = alloc(C1 * 128);
  float* POSC = alloc(2048);
  float* U2   = alloc(C1 * 128);
  float* Y2   = alloc(C1 * 128);
  float* SS   = alloc(9 * 256);
  unsigned short* COL  = (unsigned short*)alloc(E_TOT / 2 + 64);  // u16 src packets
  unsigned short* ERNK = (unsigned short*)alloc(E_TOT / 2 + 64);  // u16 edge ranks
  int* ROWS = (int*)alloc(N_NODES + 8);
  int* PART = (int*)alloc(256);
  int* CLUS = (int*)alloc(N_NODES);
  int* NB   = (int*)alloc(N_NODES);             // cluster node buckets
  int* COFF = (int*)alloc(C1 + 8);
  // ---- zero zone ----
  int* ZZ = (int*)(wsf + o);
  int*      DEG  = (int*)alloc(N_NODES);        // accumulated by count_deg merge
  float*    STAT = alloc((size_t)9 * NSTRIPE * 256);
  int*      CCNT = (int*)alloc(512);
  int*      CCUR = (int*)alloc(512);
  float*    PSUM = alloc(2048);
  int*      PF   = (int*)alloc(C1 * 64);
  unsigned* XOE  = (unsigned*)alloc(128 * 128);
  int zz_n = (int)((int*)(wsf + o) - ZZ);

  zero_kernel<<<cdiv(zz_n, 256), 256, 0, stream>>>(ZZ, zz_n);

  // clusters first (needed by fused fill_csr pair flags)
  pool5_a<<<cdiv(N_NODES, 256), 256, 0, stream>>>(POS, BAT, CLUS, CCNT, PSUM);
  cluster_scan<<<1, C1, 0, stream>>>(CCNT, COFF);
  cluster_fill<<<cdiv(N_NODES, 256), 256, 0, stream>>>(CLUS, COFF, CCUR, NB);

  // CSR build (LDS chunk count + contiguous merge -> scan -> atomic-free fill)
  count_deg<<<8 * NCHUNK, 1024, 0, stream>>>(DST, DEG, ERNK);
  scan1<<<NB_SCAN, 256, 0, stream>>>(DEG, ROWS, PART);
  scan2<<<1, 1, 0, stream>>>(PART);
  scan3<<<cdiv(N_NODES, 256), 256, 0, stream>>>(ROWS, PART);
  dim3 gF(8 * cdiv(EPG_TOT, 256));
  fill_csr<<<gF, 256, 0, stream>>>(SRC, DST, CLUS, ERNK, ROWS, COL, PF);

  dim3 gE(8 * (NPG / 4)), bE(256);
  dim3 gE16(8 * cdiv(NPG, 16));
  dim3 gT(8 * cdiv(NPG, 32)), bT(256);   // R=8 swizzled grid: 391 blocks/graph
  dim3 gC(cdiv(C1, 32));                 // coarse R=8 grid

  const size_t LSTAT = (size_t)NSTRIPE * 256;
  const float invN = 1.f / N_NODES;
  auto fin = [&](int li, int cout, float invn){
    bn_finalize<<<128, 64, 0, stream>>>(STAT + li * LSTAT, GG[li], BB[li], cout, invn, SS + li * 256);
  };

  // ---- layer 1: 1 -> 16 ----
  node1_kernel<<<cdiv(N_NODES * 16, 256), 256, 0, stream>>>(X, POS, WL[0], U);
  edge_agg16<<<gE16, bE, 0, stream>>>(U, COL, WL[0] + 16, ROWS, POS, AG);
  gemm_tile<8, 16, 16, true, true, false, false, true><<<gT, bT, 0, stream>>>(
      AG, WG[0], nullptr, nullptr, nullptr, nullptr, nullptr, AG, STAT + 0 * LSTAT, N_NODES);
  fin(0, 16, invN);

  // ---- layer 2: 16 -> 64 ----
  gemm_tile<8, 16, 64, false, false, true, true, true><<<gT, bT, 0, stream>>>(
      AG, WL[1], SS + 0 * 256, nullptr, nullptr, POS, WL[1] + 16 * 64, U, nullptr, N_NODES);
  edge_aggN<1><<<gE, bE, 0, stream>>>(U, 6, COL, WL[1] + 16 * 64, 64, ROWS, POS, AG);
  gemm_tile<8, 64, 64, true, true, false, false, true><<<gT, bT, 0, stream>>>(
      AG, WG[1], nullptr, nullptr, nullptr, nullptr, nullptr, AG, STAT + 1 * LSTAT, N_NODES);
  fin(1, 64, invN);

  // ---- layer 3: 64 -> 64  (side-writes h2 -> F1 for the L5 residual) ----
  gemm_tile<8, 64, 64, false, false, true, true, true><<<gT, bT, 0, stream>>>(
      AG, WL[2], SS + 1 * 256, nullptr, F1, POS, WL[2] + 64 * 64, U, nullptr, N_NODES);
  edge_aggN<1><<<gE, bE, 0, stream>>>(U, 6, COL, WL[2] + 64 * 64, 64, ROWS, POS, AG);
  gemm_tile<8, 64, 64, true, true, false, false, true><<<gT, bT, 0, stream>>>(
      AG, WG[2], nullptr, nullptr, nullptr, nullptr, nullptr, AG, STAT + 2 * LSTAT, N_NODES);
  fin(2, 64, invN);

  // ---- layer 4: 64 -> 64 ----
  gemm_tile<8, 64, 64, false, false, true, true, true><<<gT, bT, 0, stream>>>(
      AG, WL[3], SS + 2 * 256, nullptr, nullptr, POS, WL[3] + 64 * 64, U, nullptr, N_NODES);
  edge_aggN<1><<<gE, bE, 0, stream>>>(U, 6, COL, WL[3] + 64 * 64, 64, ROWS, POS, AG);
  gemm_tile<8, 64, 64, true, true, false, false, true><<<gT, bT, 0, stream>>>(
      AG, WG[3], nullptr, nullptr, nullptr, nullptr, nullptr, AG, STAT + 3 * LSTAT, N_NODES);
  fin(3, 64, invN);

  // ---- layer 5: 64 -> 128  (input = act4 + h2 residual; ONE 128-ch edge pass)
  gemm_tile<8, 64, 128, false, false, true, true, true><<<gT, bT, 0, stream>>>(
      AG, WL[4], SS + 3 * 256, F1, nullptr, POS, WL[4] + 64 * 128, U, nullptr, N_NODES);
  edge_aggN<2><<<gE, bE, 0, stream>>>(U, 7, COL, WL[4] + 64 * 128, 128, ROWS, POS, AG);
  gemm_tile<8, 128, 128, true, true, false, false, true><<<gT, bT, 0, stream>>>(
      AG, WG[4], nullptr, nullptr, nullptr, nullptr, nullptr, AG, STAT + 4 * LSTAT, N_NODES);
  fin(4, 128, invN);

  // pool5: atomic-free cluster max (act5 fused after raw max)
  pool5_g<<<C1, 128, 0, stream>>>(AG, SS + 4 * 256, COFF, NB, CCNT, PSUM, HCF, POSC, PF);

  // ---- coarse layer 6 (u~ = HCF @ wl + posc @ w3, posw folded) ----
  gemm_tile<8, 128, 128, false, false, false, true, false><<<gC, bT, 0, stream>>>(
      HCF, WL[5], nullptr, nullptr, nullptr, POSC, WL[5] + 128 * 128, U2, nullptr, C1);
  coarse_conv<<<C1, 128, 0, stream>>>(U2, POSC, WL[5], PF, WG[5], Y2, STAT + 5 * LSTAT);
  fin(5, 128, 1.f / C1);

  // ---- coarse layer 7 (consumes act6 inline) ----
  gemm_tile<8, 128, 128, false, false, true, true, false><<<gC, bT, 0, stream>>>(
      Y2, WL[6], SS + 5 * 256, nullptr, nullptr, POSC, WL[6] + 128 * 128, U2, nullptr, C1);
  coarse_conv<<<C1, 128, 0, stream>>>(U2, POSC, WL[6], PF, WG[6], Y2, STAT + 6 * LSTAT);
  fin(6, 128, 1.f / C1);

  // pool7: act7 + hc residual applied inline
  pool7<<<C1, 128, 0, stream>>>(Y2, SS + 6 * 256, HCF, POSC, XOE);
  fc_kernel<<<80, 64, 0, stream>>>(XOE, WFC, OUT);
}